// Round 22
// baseline (124.962 us; speedup 1.0000x reference)
//
#include <hip/hip_runtime.h>
#include <hip/hip_bf16.h>
#include <stdint.h>

#define N_TOK 8192
#define D_K   1024
#define NT    16             // K-tiles of 64
#define GSTRIDE 32768        // bytes per 32-row group: 16 tiles x 64 lanes x 32B

typedef __attribute__((ext_vector_type(4)))  int   i32x4;
typedef __attribute__((ext_vector_type(8)))  int   i32x8;
typedef __attribute__((ext_vector_type(16))) float f32x16;

// fp32 -> OCP e4m3fn, RNE, with subnormal handling (inputs ~N(0,1)).
__device__ __forceinline__ unsigned int f32_to_e4m3(float x) {
  uint32_t u = __builtin_bit_cast(uint32_t, x);
  unsigned int s = (u >> 24) & 0x80u;
  float ax = __builtin_fabsf(x);
  if (ax < 0.015625f) {                    // < 2^-6: subnormal
    int q = (int)rintf(ax * 512.0f);       // 0..8 (8 -> 0x08 = 2^-6 exact)
    return s | (unsigned int)q;
  }
  uint32_t au = u & 0x7FFFFFFFu;
  uint32_t v = au + 0x7FFFFu + ((au >> 20) & 1u);   // RNE at 3 mantissa bits
  int em = (int)(v >> 20) - 960;           // rebias 127->7 (<<3)
  if (em > 0x7E) em = 0x7E;                // clamp to 448 (0x7F = NaN)
  return s | (unsigned int)em;
}

// LDS-staged permuting convert: block = (group g of 32 rows, array sel).
// Coalesced float4 reads -> fp8 scatter into 32KB LDS fragment image ->
// coalesced 16B stores. Fragment layout: A'[g][t][lane][32B], t = k>>6,
// lane = ((k>>5)&1)<<5 | (row&31), byte = k&31. Also zeroes out[0].
__global__ void __launch_bounds__(256)
convert_perm_kernel(const float* __restrict__ a, const float* __restrict__ b,
                    unsigned char* __restrict__ oa,
                    unsigned char* __restrict__ ob,
                    float* __restrict__ out) {
  __shared__ unsigned int P[8192];   // 32 KB
  const int blk = (int)blockIdx.x;   // 512 blocks
  if (blk == 0 && threadIdx.x == 0) out[0] = 0.0f;
  const int g   = blk >> 1;
  const float* __restrict__ src = (blk & 1) ? b : a;
  unsigned char* __restrict__ dst = (blk & 1) ? ob : oa;
  const int tid = threadIdx.x;

  const float4* s4 = (const float4*)src + (size_t)g * 8192;
  const int koff = (tid >> 4) * 512 + ((tid >> 3) & 1) * 256 + (tid & 7);
#pragma unroll
  for (int i = 0; i < 32; ++i) {
    float4 v = s4[i * 256 + tid];          // row i, k = tid*4 (coalesced)
    unsigned int w = f32_to_e4m3(v.x) | (f32_to_e4m3(v.y) << 8) |
                     (f32_to_e4m3(v.z) << 16) | (f32_to_e4m3(v.w) << 24);
    P[koff + i * 8] = w;
  }
  __syncthreads();
  i32x4* d4 = (i32x4*)(dst + (size_t)g * GSTRIDE);
  const i32x4* p4 = (const i32x4*)P;
#pragma unroll
  for (int i = 0; i < 8; ++i) d4[i * 256 + tid] = p4[i * 256 + tid];
}

// Fused MX-fp8 GEMM + sigmoid-contrastive loss, LDS-free, 32x32x64 MFMA.
// R21: 128x64 WAVE tile (block 256x128, 4 waves 2Mx2N). R20 audit: at
// 64x64 waves the K-loop moves 2.1GB through the vector-load return path
// (~49 B/cyc/CU = near ceiling) while MFMA needs only 29us. 128x64 waves
// raise arithmetic intensity 64->87 FLOP/B (A 4 frags + B 2 frags per
// tile for 2x FLOP), cutting load traffic to 1.57GB. acc 128 + frags 48
// regs; #pragma unroll 2 (full unroll hoists loads -> R19's 224-VGPR).
__global__ void __launch_bounds__(256)
sigc_kernel(const unsigned char* __restrict__ A8,
            const unsigned char* __restrict__ B8,
            const int* __restrict__ labA, const int* __restrict__ labB,
            const float* __restrict__ scale_p, const float* __restrict__ bias_p,
            float* __restrict__ out) {
  __shared__ int sLabA[256];
  __shared__ int sLabB[128];
  __shared__ float sPart[4];

  const int tid  = threadIdx.x;
  const int lane = tid & 63;
  const int wid  = tid >> 6;      // 0..3
  const int wr   = wid >> 1;      // 0..1 (M half: 128 rows)
  const int wc   = wid & 1;       // 0..1 (N half: 64 cols)

  // 2-D XCD region mapping on the 32x64 block grid (2048 blocks).
  const int bid = (int)blockIdx.x;
  const int xcd = bid & 7;
  const int ii  = bid >> 3;                    // 0..255
  const int rr  = (xcd >> 2) * 16 + (ii & 15); // block-row 0..31 (256 rows)
  const int cc  = (xcd & 3) * 16 + (ii >> 4);  // block-col 0..63 (128 cols)

  sLabA[tid] = labA[rr * 256 + tid];
  if (tid < 128) sLabB[tid] = labB[cc * 128 + tid];

  // Fragment base pointers: group (g) at g*GSTRIDE + lane*32; tile t at
  // +t*2048. A groups: rr*8 + wr*4 + f (f=0..3). B: cc*4 + wc*2 + nf.
  const unsigned char* aF = A8 + (size_t)(rr * 8 + wr * 4) * GSTRIDE + lane * 32;
  const unsigned char* bF = B8 + (size_t)(cc * 4 + wc * 2) * GSTRIDE + lane * 32;

  f32x16 acc00 = {0}, acc01 = {0}, acc10 = {0}, acc11 = {0};
  f32x16 acc20 = {0}, acc21 = {0}, acc30 = {0}, acc31 = {0};

#pragma unroll 2
  for (int t = 0; t < NT; ++t) {
    const int off = t * 2048;
    i32x8 fa0 = *(const i32x8*)(aF + off);
    i32x8 fa1 = *(const i32x8*)(aF + GSTRIDE + off);
    i32x8 fa2 = *(const i32x8*)(aF + 2 * GSTRIDE + off);
    i32x8 fa3 = *(const i32x8*)(aF + 3 * GSTRIDE + off);
    i32x8 fb0 = *(const i32x8*)(bF + off);
    i32x8 fb1 = *(const i32x8*)(bF + GSTRIDE + off);
    __builtin_amdgcn_s_setprio(1);
    acc00 = __builtin_amdgcn_mfma_scale_f32_32x32x64_f8f6f4(
        fa0, fb0, acc00, 0, 0, 0, 0x7F7F7F7F, 0, 0x7F7F7F7F);
    acc01 = __builtin_amdgcn_mfma_scale_f32_32x32x64_f8f6f4(
        fa0, fb1, acc01, 0, 0, 0, 0x7F7F7F7F, 0, 0x7F7F7F7F);
    acc10 = __builtin_amdgcn_mfma_scale_f32_32x32x64_f8f6f4(
        fa1, fb0, acc10, 0, 0, 0, 0x7F7F7F7F, 0, 0x7F7F7F7F);
    acc11 = __builtin_amdgcn_mfma_scale_f32_32x32x64_f8f6f4(
        fa1, fb1, acc11, 0, 0, 0, 0x7F7F7F7F, 0, 0x7F7F7F7F);
    acc20 = __builtin_amdgcn_mfma_scale_f32_32x32x64_f8f6f4(
        fa2, fb0, acc20, 0, 0, 0, 0x7F7F7F7F, 0, 0x7F7F7F7F);
    acc21 = __builtin_amdgcn_mfma_scale_f32_32x32x64_f8f6f4(
        fa2, fb1, acc21, 0, 0, 0, 0x7F7F7F7F, 0, 0x7F7F7F7F);
    acc30 = __builtin_amdgcn_mfma_scale_f32_32x32x64_f8f6f4(
        fa3, fb0, acc30, 0, 0, 0, 0x7F7F7F7F, 0, 0x7F7F7F7F);
    acc31 = __builtin_amdgcn_mfma_scale_f32_32x32x64_f8f6f4(
        fa3, fb1, acc31, 0, 0, 0, 0x7F7F7F7F, 0, 0x7F7F7F7F);
    __builtin_amdgcn_s_setprio(0);
  }

  __syncthreads();   // publish labels before epilogue

  // Epilogue: u = logit*log2e. S1 += u, S2 += |u|, p = fma(p,2^-|u|,p);
  // matches: Sm += u. loss = 0.5*(S1+S2) - Sm + log2(prod p), x ln2/N.
  // 32x32 C/D layout: col = lane&31, row = (reg&3)+8*(reg>>2)+4*(lane>>5).
  const float L2E = 1.4426950408889634f;
  const float sl2e = scale_p[0] * L2E;
  const float bl2e = bias_p[0] * L2E;
  const int colIn = lane & 31;
  const int hi32  = lane >> 5;
  const int colL0 = sLabB[wc * 64 + colIn];
  const int colL1 = sLabB[wc * 64 + 32 + colIn];

  float S1a = 0.f, S2a = 0.f, Sma = 0.f, pa = 1.0f;
  float S1b = 0.f, S2b = 0.f, Smb = 0.f, pb = 1.0f;
  float S1c = 0.f, S2c = 0.f, Smc = 0.f, pc = 1.0f;
  float S1d = 0.f, S2d = 0.f, Smd = 0.f, pd = 1.0f;

  // Chain x handles quadrants (mf, nf=0) and (mf, nf=1) -> 32 elems, p<=2^32.
#define EPI(ACC0, ACC1, MF, S1x, S2x, Smx, px) do {                        \
    _Pragma("unroll") for (int _r = 0; _r < 16; ++_r) {                    \
      const int _rowL = sLabA[wr * 128 + (MF) * 32 +                       \
                              (_r & 3) + 8 * (_r >> 2) + 4 * hi32];        \
      {                                                                    \
        const float _u = fmaf(sl2e, ACC0[_r], bl2e);                       \
        const float _au = fabsf(_u);                                       \
        S1x += _u; S2x += _au;                                             \
        px = fmaf(px, __builtin_amdgcn_exp2f(-_au), px);                   \
        Smx += (_rowL == colL0) ? _u : 0.0f;                               \
      }                                                                    \
      {                                                                    \
        const float _u = fmaf(sl2e, ACC1[_r], bl2e);                       \
        const float _au = fabsf(_u);                                       \
        S1x += _u; S2x += _au;                                             \
        px = fmaf(px, __builtin_amdgcn_exp2f(-_au), px);                   \
        Smx += (_rowL == colL1) ? _u : 0.0f;                               \
      }                                                                    \
    } } while (0)

  EPI(acc00, acc01, 0, S1a, S2a, Sma, pa);
  EPI(acc10, acc11, 1, S1b, S2b, Smb, pb);
  EPI(acc20, acc21, 2, S1c, S2c, Smc, pc);
  EPI(acc30, acc31, 3, S1d, S2d, Smd, pd);

  const float S1 = (S1a + S1b) + (S1c + S1d);
  const float S2 = (S2a + S2b) + (S2c + S2d);
  const float Sm = (Sma + Smb) + (Smc + Smd);
  float loss = 0.5f * (S1 + S2) - Sm +
               __builtin_amdgcn_logf(pa * pb) +
               __builtin_amdgcn_logf(pc * pd);

#pragma unroll
  for (int off = 32; off > 0; off >>= 1) loss += __shfl_down(loss, off, 64);
  if (lane == 0) sPart[wid] = loss;
  __syncthreads();
  if (tid == 0) {
    const float s = (sPart[0] + sPart[1]) + (sPart[2] + sPart[3]);
    atomicAdd(out, s * (0.6931471805599453f / (float)N_TOK));
  }
}

extern "C" void kernel_launch(void* const* d_in, const int* in_sizes, int n_in,
                              void* d_out, int out_size, void* d_ws, size_t ws_size,
                              hipStream_t stream) {
  const float* a  = (const float*)d_in[0];
  const float* b  = (const float*)d_in[1];
  const int*   la = (const int*)d_in[2];
  const int*   lb = (const int*)d_in[3];
  const float* sc = (const float*)d_in[4];
  const float* bi = (const float*)d_in[5];
  float* out = (float*)d_out;

  unsigned char* wa = (unsigned char*)d_ws;          // fp8 A', 8 MB
  unsigned char* wb = wa + (size_t)N_TOK * D_K;      // fp8 B', 8 MB

  convert_perm_kernel<<<512, 256, 0, stream>>>(a, b, wa, wb, out);
  const int grid = (N_TOK / 256) * (N_TOK / 128);    // 2048
  sigc_kernel<<<grid, 256, 0, stream>>>(wa, wb, la, lb, sc, bi, out);
}